// Round 4
// baseline (226.061 us; speedup 1.0000x reference)
//
#include <hip/hip_runtime.h>
#include <math.h>

// CORM attention v4, MI355X / gfx950.
// prep : fp32 -> bf16 tile images (exact swizzled LDS layout) for Q(hi,lo), K(hi), V^T
// flash: swapped-QK, 4 waves x 32 q-rows (R=32 halves LDS amplification), dbuf pipeline
// corm : bf16x3 scores vs T, 4 waves x 32 kv-rows, dbuf pipeline.

#define HN   32
#define DH   128
#define SEQ  2048
#define NBLK 32            // SEQ / 64
#define KB   64
#define TILE_SHORTS 8192   // 64 * 128
#define SCALEF 0.08838834764831843f   // 1/sqrt(128)
#define SC2   0.1275174072417346f     // SCALEF * log2(e)
#define LN2   0.6931471805599453f

typedef __attribute__((ext_vector_type(4))) float f4;
typedef __attribute__((ext_vector_type(8))) short s8;

typedef __attribute__((address_space(3))) unsigned lds_u32;
typedef const __attribute__((address_space(1))) unsigned glob_u32;

__device__ __forceinline__ short f2bf(float x) {
  union { float f; unsigned u; } a; a.f = x;
  unsigned r = a.u + 0x7FFFu + ((a.u >> 16) & 1u);  // RNE
  return (short)(r >> 16);
}
__device__ __forceinline__ float bf2f(short h) {
  union { unsigned u; float f; } a;
  a.u = ((unsigned)(unsigned short)h) << 16;
  return a.f;
}
// swizzled short-index in a row-major [R][Cshort] bf16 tile: byte ^= (row&7)<<4
__device__ __forceinline__ int swz(int row, int colShort, int Cshort) {
  int byte = (colShort * 2) ^ ((row & 7) << 4);
  return row * Cshort + (byte >> 1);
}
__device__ __forceinline__ float lanef(float v, int srcLane) {
  return __builtin_bit_cast(float,
      __builtin_amdgcn_ds_bpermute(srcLane * 4, __builtin_bit_cast(int, v)));
}
// 256-thread cooperative stage of one 16KB tile image (4 x 16B per thread)
__device__ __forceinline__ void stage256(const char* g, char* l, int tid) {
  int wb = (tid >> 6) * 4096, lo = (tid & 63) * 16;
#pragma unroll
  for (int i = 0; i < 4; ++i)
    __builtin_amdgcn_global_load_lds((glob_u32*)(g + wb + i * 1024 + lo),
                                     (lds_u32*)(l + wb + i * 1024), 16, 0, 0);
}

// ---------------------------------------------------------------- prep
__global__ __launch_bounds__(256) void prep_qkv(
    const float* __restrict__ gQ, const float* __restrict__ gK,
    const float* __restrict__ gV, short* __restrict__ oQh,
    short* __restrict__ oQl, short* __restrict__ oKs, short* __restrict__ oVt)
{
  __shared__ short Vs[64][136];
  const int blk = blockIdx.x, h = blockIdx.y, tid = threadIdx.x;
  const size_t toff = ((size_t)h * NBLK + blk) * TILE_SHORTS;

#pragma unroll
  for (int i = 0; i < 4; ++i) {
    int c = tid + 256 * i, r = c >> 4, c0 = (c & 15) * 8;
    size_t rowoff = ((size_t)(blk * 64 + r) * HN + h) * DH + c0;
    {  // Q hi/lo
      f4 a = *(const f4*)(gQ + rowoff), b = *(const f4*)(gQ + rowoff + 4);
      s8 oh, ol;
#pragma unroll
      for (int e = 0; e < 4; ++e) {
        short hi = f2bf(a[e]); oh[e] = hi; ol[e] = f2bf(a[e] - bf2f(hi));
        short h2 = f2bf(b[e]); oh[4+e] = h2; ol[4+e] = f2bf(b[e] - bf2f(h2));
      }
      *(s8*)&oQh[toff + swz(r, c0, DH)] = oh;
      *(s8*)&oQl[toff + swz(r, c0, DH)] = ol;
    }
    {  // K hi
      f4 a = *(const f4*)(gK + rowoff), b = *(const f4*)(gK + rowoff + 4);
      s8 o;
#pragma unroll
      for (int e = 0; e < 4; ++e) { o[e] = f2bf(a[e]); o[4+e] = f2bf(b[e]); }
      *(s8*)&oKs[toff + swz(r, c0, DH)] = o;
    }
    {  // V -> LDS (linear, padded)
      f4 a = *(const f4*)(gV + rowoff), b = *(const f4*)(gV + rowoff + 4);
      s8 o;
#pragma unroll
      for (int e = 0; e < 4; ++e) { o[e] = f2bf(a[e]); o[4+e] = f2bf(b[e]); }
      *(s8*)&Vs[r][c0] = o;
    }
  }
  __syncthreads();
#pragma unroll
  for (int i = 0; i < 4; ++i) {
    int c = tid + 256 * i, d = c >> 3, k0 = (c & 7) * 8;
    s8 o;
#pragma unroll
    for (int j = 0; j < 8; ++j) o[j] = Vs[k0 + j][d];
    *(s8*)&oVt[toff + swz(d, k0, KB)] = o;
  }
}

// ---------------------------------------------------------------- kernel 1
// 4 waves x 32 q-rows (two 16-row groups g). Swapped QK: lane owns q = q0+g*16+l15.
__global__ __launch_bounds__(256, 2) void flash_fwd(
    const short* __restrict__ gQh, const short* __restrict__ gKs,
    const short* __restrict__ gVt, float* __restrict__ gO,
    float* __restrict__ gT)
{
  __shared__ short Ks[2][TILE_SHORTS];   // 32 KB
  __shared__ short Vt[2][TILE_SHORTS];   // 32 KB
  __shared__ short Ps[4][2][1024];       // 16 KB

  const int b = (gridDim.x - 1) - blockIdx.x, h = blockIdx.y;  // heavy first
  const int tid = threadIdx.x;
  const int wv = tid >> 6, ln = tid & 63, l15 = ln & 15, l4 = ln >> 4;
  const int q0 = b * 128 + wv * 32;       // wave's first q row (32 rows)
  const int ntile = 2 * b + 2;
  const size_t hbase = (size_t)h * NBLK * TILE_SHORTS;

  // Q B-frags for the wave's two 16-row groups (from pre-swizzled global image)
  const int qt = 2 * b + (wv >> 1);               // tile holding this wave's rows
  const short* qtile = gQh + hbase + (size_t)qt * TILE_SHORTS;
  s8 qf[2][4];
#pragma unroll
  for (int g = 0; g < 2; ++g)
#pragma unroll
    for (int dt = 0; dt < 4; ++dt)
      qf[g][dt] = *(const s8*)&qtile[swz((wv & 1) * 32 + g * 16 + l15,
                                         dt * 32 + l4 * 8, DH)];

  f4 oacc[2][8];
#pragma unroll
  for (int g = 0; g < 2; ++g)
#pragma unroll
    for (int i = 0; i < 8; ++i) { oacc[g][i][0]=0.f; oacc[g][i][1]=0.f; oacc[g][i][2]=0.f; oacc[g][i][3]=0.f; }
  float m1[2] = {-INFINITY, -INFINITY}, l1[2] = {0.f, 0.f};
  const int abase = (ln & 48) + 4 * l4;  // bpermute src: lane with l15 = 4*l4+j

  // prologue: tile 0 -> buf 0  (8 loads/thread outstanding)
  stage256((const char*)(gKs + hbase), (char*)&Ks[0][0], tid);
  stage256((const char*)(gVt + hbase), (char*)&Vt[0][0], tid);

  for (int t = 0; t < ntile; ++t) {
    const int cur = t & 1;
    if (t + 1 < ntile) {
      stage256((const char*)(gKs + hbase + (size_t)(t + 1) * TILE_SHORTS), (char*)&Ks[cur ^ 1][0], tid);
      stage256((const char*)(gVt + hbase + (size_t)(t + 1) * TILE_SHORTS), (char*)&Vt[cur ^ 1][0], tid);
      asm volatile("s_waitcnt vmcnt(8)" ::: "memory");   // tile t done, t+1 in flight
    } else {
      asm volatile("s_waitcnt vmcnt(0)" ::: "memory");
    }
    __builtin_amdgcn_s_barrier();
    __builtin_amdgcn_sched_barrier(0);

    if (t * 64 <= q0 + 31) {  // wave has unmasked rows in this tile
      // ---- S^T = K Q^T : D[kv = n*16+4*l4+j][q = g*16+l15]
      f4 sacc[2][4];
#pragma unroll
      for (int g = 0; g < 2; ++g)
#pragma unroll
        for (int n = 0; n < 4; ++n) { sacc[g][n][0]=0.f; sacc[g][n][1]=0.f; sacc[g][n][2]=0.f; sacc[g][n][3]=0.f; }
      __builtin_amdgcn_s_setprio(1);
#pragma unroll
      for (int n = 0; n < 4; ++n)
#pragma unroll
        for (int dt = 0; dt < 4; ++dt) {
          s8 kf = *(const s8*)&Ks[cur][swz(n * 16 + l15, dt * 32 + l4 * 8, DH)];
          sacc[0][n] = __builtin_amdgcn_mfma_f32_16x16x32_bf16(kf, qf[0][dt], sacc[0][n], 0, 0, 0);
          sacc[1][n] = __builtin_amdgcn_mfma_f32_16x16x32_bf16(kf, qf[1][dt], sacc[1][n], 0, 0, 0);
        }
      __builtin_amdgcn_s_setprio(0);

      // ---- log2-domain scores + mask + two independent softmax chains
      float z[2][4][4], mt[2], alpha[2], mold[2];
      const bool needmask = (t * 64 + 63 > q0);
#pragma unroll
      for (int g = 0; g < 2; ++g) {
        const int qg = q0 + g * 16 + l15;
        if (needmask) {
#pragma unroll
          for (int n = 0; n < 4; ++n)
#pragma unroll
            for (int j = 0; j < 4; ++j) {
              int kv = t * 64 + n * 16 + 4 * l4 + j;
              float v = sacc[g][n][j] * SC2;
              z[g][n][j] = (kv > qg) ? -INFINITY : v;
            }
        } else {
#pragma unroll
          for (int n = 0; n < 4; ++n)
#pragma unroll
            for (int j = 0; j < 4; ++j) z[g][n][j] = sacc[g][n][j] * SC2;
        }
        float a0 = fmaxf(fmaxf(z[g][0][0], z[g][0][1]), fmaxf(z[g][0][2], z[g][0][3]));
        float a1 = fmaxf(fmaxf(z[g][1][0], z[g][1][1]), fmaxf(z[g][1][2], z[g][1][3]));
        float a2 = fmaxf(fmaxf(z[g][2][0], z[g][2][1]), fmaxf(z[g][2][2], z[g][2][3]));
        float a3 = fmaxf(fmaxf(z[g][3][0], z[g][3][1]), fmaxf(z[g][3][2], z[g][3][3]));
        float m = fmaxf(fmaxf(a0, a1), fmaxf(a2, a3));
        m = fmaxf(m, __shfl_xor(m, 16));
        m = fmaxf(m, __shfl_xor(m, 32));
        mt[g] = m;
        mold[g] = m1[g];
        float mn = fmaxf(m1[g], m);
        alpha[g] = exp2f(m1[g] - mn);   // -inf - finite -> 0, never NaN
        m1[g] = mn;
        float s0 = 0.f;
#pragma unroll
        for (int n = 0; n < 4; ++n) {
#pragma unroll
          for (int j = 0; j < 4; ++j) { z[g][n][j] = exp2f(z[g][n][j] - mn); }
          s0 += (z[g][n][0] + z[g][n][1]) + (z[g][n][2] + z[g][n][3]);
        }
        s0 += __shfl_xor(s0, 16);
        s0 += __shfl_xor(s0, 32);
        l1[g] = l1[g] * alpha[g] + s0;
      }

      // ---- rescale oacc only if some lane's max actually grew (else alpha==1)
      if (__any((mt[0] > mold[0]) || (mt[1] > mold[1]))) {
#pragma unroll
        for (int g = 0; g < 2; ++g) {
          float aj[4];
#pragma unroll
          for (int j = 0; j < 4; ++j) aj[j] = lanef(alpha[g], abase + j);
#pragma unroll
          for (int ds = 0; ds < 8; ++ds)
#pragma unroll
            for (int j = 0; j < 4; ++j) oacc[g][ds][j] *= aj[j];
        }
      }

      // ---- P -> wave-local LDS tiles [q=l15][kv], packed b64 writes
#pragma unroll
      for (int g = 0; g < 2; ++g) {
        short* pw = &Ps[wv][g][0];
#pragma unroll
        for (int n = 0; n < 4; ++n) {
          unsigned lo, hi;
          asm("v_cvt_pk_bf16_f32 %0, %1, %2" : "=v"(lo) : "v"(z[g][n][0]), "v"(z[g][n][1]));
          asm("v_cvt_pk_bf16_f32 %0, %1, %2" : "=v"(hi) : "v"(z[g][n][2]), "v"(z[g][n][3]));
          uint2 w; w.x = lo; w.y = hi;
          *(uint2*)&pw[swz(l15, n * 16 + 4 * l4, KB)] = w;
        }
      }

      // ---- PV: oacc[g][q=4*l4+j][d=ds*16+l15] += P[g] * V  (V frags shared)
      s8 pa00 = *(const s8*)&Ps[wv][0][swz(l15, l4 * 8, KB)];
      s8 pa01 = *(const s8*)&Ps[wv][0][swz(l15, 32 + l4 * 8, KB)];
      s8 pa10 = *(const s8*)&Ps[wv][1][swz(l15, l4 * 8, KB)];
      s8 pa11 = *(const s8*)&Ps[wv][1][swz(l15, 32 + l4 * 8, KB)];
      __builtin_amdgcn_s_setprio(1);
#pragma unroll
      for (int ds = 0; ds < 8; ++ds) {
        s8 vb0 = *(const s8*)&Vt[cur][swz(ds * 16 + l15, l4 * 8, KB)];
        oacc[0][ds] = __builtin_amdgcn_mfma_f32_16x16x32_bf16(pa00, vb0, oacc[0][ds], 0, 0, 0);
        oacc[1][ds] = __builtin_amdgcn_mfma_f32_16x16x32_bf16(pa10, vb0, oacc[1][ds], 0, 0, 0);
        s8 vb1 = *(const s8*)&Vt[cur][swz(ds * 16 + l15, 32 + l4 * 8, KB)];
        oacc[0][ds] = __builtin_amdgcn_mfma_f32_16x16x32_bf16(pa01, vb1, oacc[0][ds], 0, 0, 0);
        oacc[1][ds] = __builtin_amdgcn_mfma_f32_16x16x32_bf16(pa11, vb1, oacc[1][ds], 0, 0, 0);
      }
      __builtin_amdgcn_s_setprio(0);
    }
    asm volatile("s_waitcnt lgkmcnt(0)" ::: "memory");
    __builtin_amdgcn_s_barrier();
    __builtin_amdgcn_sched_barrier(0);
  }

  // ---- epilogue
#pragma unroll
  for (int g = 0; g < 2; ++g) {
    float linv = 1.0f / l1[g];
    float lj[4];
#pragma unroll
    for (int j = 0; j < 4; ++j) lj[j] = lanef(linv, abase + j);
#pragma unroll
    for (int j = 0; j < 4; ++j) {
      int qg = q0 + g * 16 + 4 * l4 + j;
      float* orow = gO + ((size_t)qg * HN + h) * DH;
#pragma unroll
      for (int ds = 0; ds < 8; ++ds)
        orow[ds * 16 + l15] = oacc[g][ds][j] * lj[j];
    }
    if (l4 == 0) {
      int qg = q0 + g * 16 + l15;
      gT[h * SEQ + qg] = LN2 * (m1[g] + log2f(l1[g])) - logf((float)(qg + 1));
    }
  }
}

// ---------------------------------------------------------------- kernel 2
// 4 waves x 32 kv-rows; K rows hi/lo in regs; Q(hi,lo) tiles dbuf'd.
__global__ __launch_bounds__(256, 2) void corm_fwd(
    const float* __restrict__ gK, const short* __restrict__ gQh,
    const short* __restrict__ gQl, const float* __restrict__ gT,
    float* __restrict__ gC)
{
  __shared__ short Qh[2][TILE_SHORTS];   // 32 KB
  __shared__ short Ql[2][TILE_SHORTS];   // 32 KB
  __shared__ float Tt[SEQ];              // 8 KB

  const int b = blockIdx.x, h = blockIdx.y;   // b=0 heaviest, first
  const int kv0 = b * 128;
  const int tid = threadIdx.x;
  const int wv = tid >> 6, ln = tid & 63, l15 = ln & 15, l4 = ln >> 4;
  const int kvw = kv0 + wv * 32;               // wave's first kv row (32 rows)

  // wave's 32 K rows as hi/lo A-frags (two 16-row groups)
  s8 khi[2][4], klo[2][4];
#pragma unroll
  for (int g = 0; g < 2; ++g) {
    const float* krow = gK + ((size_t)(kvw + g * 16 + l15) * HN + h) * DH;
#pragma unroll
    for (int dt = 0; dt < 4; ++dt) {
      f4 a = *(const f4*)(krow + dt * 32 + l4 * 8);
      f4 bb = *(const f4*)(krow + dt * 32 + l4 * 8 + 4);
#pragma unroll
      for (int e = 0; e < 4; ++e) {
        short hi = f2bf(a[e]); khi[g][dt][e] = hi; klo[g][dt][e] = f2bf(a[e] - bf2f(hi));
        short h2 = f2bf(bb[e]); khi[g][dt][4+e] = h2; klo[g][dt][4+e] = f2bf(bb[e] - bf2f(h2));
      }
    }
  }
  for (int i = tid; i < SEQ - kv0; i += 256) Tt[i] = gT[h * SEQ + kv0 + i];
  __syncthreads();

  const size_t hbase = (size_t)h * NBLK * TILE_SHORTS;
  const int t0 = 2 * b;
  stage256((const char*)(gQh + hbase + (size_t)t0 * TILE_SHORTS), (char*)&Qh[t0 & 1][0], tid);
  stage256((const char*)(gQl + hbase + (size_t)t0 * TILE_SHORTS), (char*)&Ql[t0 & 1][0], tid);

  int fired[2][4] = {{0,0,0,0},{0,0,0,0}};

  for (int t = t0; t < NBLK; ++t) {
    const int cur = t & 1;
    if (t + 1 < NBLK) {
      stage256((const char*)(gQh + hbase + (size_t)(t + 1) * TILE_SHORTS), (char*)&Qh[cur ^ 1][0], tid);
      stage256((const char*)(gQl + hbase + (size_t)(t + 1) * TILE_SHORTS), (char*)&Ql[cur ^ 1][0], tid);
      asm volatile("s_waitcnt vmcnt(8)" ::: "memory");
    } else {
      asm volatile("s_waitcnt vmcnt(0)" ::: "memory");
    }
    __builtin_amdgcn_s_barrier();
    __builtin_amdgcn_sched_barrier(0);

    if (kvw <= t * 64 + 63) {  // some q in tile >= wave's kv rows
      __builtin_amdgcn_s_setprio(1);
#pragma unroll
      for (int n = 0; n < 4; ++n) {
        f4 acc0, acc1;
        acc0[0]=0.f; acc0[1]=0.f; acc0[2]=0.f; acc0[3]=0.f;
        acc1[0]=0.f; acc1[1]=0.f; acc1[2]=0.f; acc1[3]=0.f;
#pragma unroll
        for (int dt = 0; dt < 4; ++dt) {
          s8 qhb = *(const s8*)&Qh[cur][swz(n * 16 + l15, dt * 32 + l4 * 8, DH)];
          s8 qlb = *(const s8*)&Ql[cur][swz(n * 16 + l15, dt * 32 + l4 * 8, DH)];
          acc0 = __builtin_amdgcn_mfma_f32_16x16x32_bf16(khi[0][dt], qhb, acc0, 0, 0, 0);
          acc0 = __builtin_amdgcn_mfma_f32_16x16x32_bf16(khi[0][dt], qlb, acc0, 0, 0, 0);
          acc0 = __builtin_amdgcn_mfma_f32_16x16x32_bf16(klo[0][dt], qhb, acc0, 0, 0, 0);
          acc1 = __builtin_amdgcn_mfma_f32_16x16x32_bf16(khi[1][dt], qhb, acc1, 0, 0, 0);
          acc1 = __builtin_amdgcn_mfma_f32_16x16x32_bf16(khi[1][dt], qlb, acc1, 0, 0, 0);
          acc1 = __builtin_amdgcn_mfma_f32_16x16x32_bf16(klo[1][dt], qhb, acc1, 0, 0, 0);
        }
        int qg = t * 64 + n * 16 + l15;
        float Tq = Tt[qg - kv0];
#pragma unroll
        for (int j = 0; j < 4; ++j) {
          int kvr0 = kvw + 4 * l4 + j;
          if (qg >= kvr0 && acc0[j] * SCALEF >= Tq) fired[0][j] = 1;
          int kvr1 = kvw + 16 + 4 * l4 + j;
          if (qg >= kvr1 && acc1[j] * SCALEF >= Tq) fired[1][j] = 1;
        }
      }
      __builtin_amdgcn_s_setprio(0);
    }
    asm volatile("s_waitcnt lgkmcnt(0)" ::: "memory");
    __builtin_amdgcn_s_barrier();
    __builtin_amdgcn_sched_barrier(0);
  }

#pragma unroll
  for (int g = 0; g < 2; ++g)
#pragma unroll
    for (int j = 0; j < 4; ++j) {
      fired[g][j] |= __shfl_xor(fired[g][j], 1, 16);
      fired[g][j] |= __shfl_xor(fired[g][j], 2, 16);
      fired[g][j] |= __shfl_xor(fired[g][j], 4, 16);
      fired[g][j] |= __shfl_xor(fired[g][j], 8, 16);
    }
  if (l15 == 0) {
#pragma unroll
    for (int g = 0; g < 2; ++g)
#pragma unroll
      for (int j = 0; j < 4; ++j)
        gC[h * SEQ + kvw + g * 16 + 4 * l4 + j] = fired[g][j] ? 1.0f : 0.0f;
  }
}

// ---------------------------------------------------------------- launcher
extern "C" void kernel_launch(void* const* d_in, const int* in_sizes, int n_in,
                              void* d_out, int out_size, void* d_ws, size_t ws_size,
                              hipStream_t stream) {
  const float* q = (const float*)d_in[0];
  const float* k = (const float*)d_in[1];
  const float* v = (const float*)d_in[2];
  // d_in[3] = corm_mask: row i is exactly 1/(i+1); folded analytically into T.
  float* out  = (float*)d_out;
  float* corm = out + (size_t)SEQ * HN * DH;

  const size_t ARR = (size_t)HN * NBLK * TILE_SHORTS;  // 8,388,608 shorts / array
  short* Qh = (short*)d_ws;
  short* Ql = Qh + ARR;
  short* Ks = Ql + ARR;
  short* Vt = Ks + ARR;
  float* T  = (float*)(Vt + ARR);   // total ~64.3 MiB of ws

  prep_qkv<<<dim3(NBLK, HN), dim3(256), 0, stream>>>(q, k, v, Qh, Ql, Ks, Vt);
  flash_fwd<<<dim3(16, HN), dim3(256), 0, stream>>>(Qh, Ks, Vt, out, T);
  corm_fwd<<<dim3(16, HN), dim3(256), 0, stream>>>(k, Qh, Ql, T, corm);
}

// Round 5
// 221.623 us; speedup vs baseline: 1.0200x; 1.0200x over previous
//
#include <hip/hip_runtime.h>
#include <math.h>

// CORM attention v5, MI355X / gfx950.
// v5 = v4 + LDS <= 64KB so TWO blocks fit per CU (v3/v4 ran 1 block/CU:
// 2 x 80KB > 160KB pool after reservation -> lockstep barriers, exposed latency).
// flash: K dbuf + V single-buffer (staged & waited in same interval), Ps 16KB = 64KB.
// corm : Qh dbuf + Ql single-buffer + Tt = 56KB.

#define HN   32
#define DH   128
#define SEQ  2048
#define NBLK 32            // SEQ / 64
#define KB   64
#define TILE_SHORTS 8192   // 64 * 128
#define SCALEF 0.08838834764831843f   // 1/sqrt(128)
#define SC2   0.1275174072417346f     // SCALEF * log2(e)
#define LN2   0.6931471805599453f

typedef __attribute__((ext_vector_type(4))) float f4;
typedef __attribute__((ext_vector_type(8))) short s8;

typedef __attribute__((address_space(3))) unsigned lds_u32;
typedef const __attribute__((address_space(1))) unsigned glob_u32;

__device__ __forceinline__ short f2bf(float x) {
  union { float f; unsigned u; } a; a.f = x;
  unsigned r = a.u + 0x7FFFu + ((a.u >> 16) & 1u);  // RNE
  return (short)(r >> 16);
}
__device__ __forceinline__ float bf2f(short h) {
  union { unsigned u; float f; } a;
  a.u = ((unsigned)(unsigned short)h) << 16;
  return a.f;
}
// swizzled short-index in a row-major [R][Cshort] bf16 tile: byte ^= (row&7)<<4
__device__ __forceinline__ int swz(int row, int colShort, int Cshort) {
  int byte = (colShort * 2) ^ ((row & 7) << 4);
  return row * Cshort + (byte >> 1);
}
__device__ __forceinline__ float lanef(float v, int srcLane) {
  return __builtin_bit_cast(float,
      __builtin_amdgcn_ds_bpermute(srcLane * 4, __builtin_bit_cast(int, v)));
}
// 256-thread cooperative stage of one 16KB tile image (4 x 16B per thread)
__device__ __forceinline__ void stage256(const char* g, char* l, int tid) {
  int wb = (tid >> 6) * 4096, lo = (tid & 63) * 16;
#pragma unroll
  for (int i = 0; i < 4; ++i)
    __builtin_amdgcn_global_load_lds((glob_u32*)(g + wb + i * 1024 + lo),
                                     (lds_u32*)(l + wb + i * 1024), 16, 0, 0);
}

// ---------------------------------------------------------------- prep
__global__ __launch_bounds__(256) void prep_qkv(
    const float* __restrict__ gQ, const float* __restrict__ gK,
    const float* __restrict__ gV, short* __restrict__ oQh,
    short* __restrict__ oQl, short* __restrict__ oKs, short* __restrict__ oVt)
{
  __shared__ short Vs[64][136];
  const int blk = blockIdx.x, h = blockIdx.y, tid = threadIdx.x;
  const size_t toff = ((size_t)h * NBLK + blk) * TILE_SHORTS;

#pragma unroll
  for (int i = 0; i < 4; ++i) {
    int c = tid + 256 * i, r = c >> 4, c0 = (c & 15) * 8;
    size_t rowoff = ((size_t)(blk * 64 + r) * HN + h) * DH + c0;
    {  // Q hi/lo
      f4 a = *(const f4*)(gQ + rowoff), b = *(const f4*)(gQ + rowoff + 4);
      s8 oh, ol;
#pragma unroll
      for (int e = 0; e < 4; ++e) {
        short hi = f2bf(a[e]); oh[e] = hi; ol[e] = f2bf(a[e] - bf2f(hi));
        short h2 = f2bf(b[e]); oh[4+e] = h2; ol[4+e] = f2bf(b[e] - bf2f(h2));
      }
      *(s8*)&oQh[toff + swz(r, c0, DH)] = oh;
      *(s8*)&oQl[toff + swz(r, c0, DH)] = ol;
    }
    {  // K hi
      f4 a = *(const f4*)(gK + rowoff), b = *(const f4*)(gK + rowoff + 4);
      s8 o;
#pragma unroll
      for (int e = 0; e < 4; ++e) { o[e] = f2bf(a[e]); o[4+e] = f2bf(b[e]); }
      *(s8*)&oKs[toff + swz(r, c0, DH)] = o;
    }
    {  // V -> LDS (linear, padded)
      f4 a = *(const f4*)(gV + rowoff), b = *(const f4*)(gV + rowoff + 4);
      s8 o;
#pragma unroll
      for (int e = 0; e < 4; ++e) { o[e] = f2bf(a[e]); o[4+e] = f2bf(b[e]); }
      *(s8*)&Vs[r][c0] = o;
    }
  }
  __syncthreads();
#pragma unroll
  for (int i = 0; i < 4; ++i) {
    int c = tid + 256 * i, d = c >> 3, k0 = (c & 7) * 8;
    s8 o;
#pragma unroll
    for (int j = 0; j < 8; ++j) o[j] = Vs[k0 + j][d];
    *(s8*)&oVt[toff + swz(d, k0, KB)] = o;
  }
}

// ---------------------------------------------------------------- kernel 1
// 4 waves x 32 q-rows (two 16-row groups g). Swapped QK: lane owns q = q0+g*16+l15.
__global__ __launch_bounds__(256, 2) void flash_fwd(
    const short* __restrict__ gQh, const short* __restrict__ gKs,
    const short* __restrict__ gVt, float* __restrict__ gO,
    float* __restrict__ gT)
{
  __shared__ short Ks[2][TILE_SHORTS];   // 32 KB (dbuf)
  __shared__ short Vt[TILE_SHORTS];      // 16 KB (single)
  __shared__ short Ps[4][2][1024];       // 16 KB            -> 64 KB total

  const int b = (gridDim.x - 1) - blockIdx.x, h = blockIdx.y;  // heavy first
  const int tid = threadIdx.x;
  const int wv = tid >> 6, ln = tid & 63, l15 = ln & 15, l4 = ln >> 4;
  const int q0 = b * 128 + wv * 32;       // wave's first q row (32 rows)
  const int ntile = 2 * b + 2;
  const size_t hbase = (size_t)h * NBLK * TILE_SHORTS;

  // Q B-frags for the wave's two 16-row groups (from pre-swizzled global image)
  const int qt = 2 * b + (wv >> 1);
  const short* qtile = gQh + hbase + (size_t)qt * TILE_SHORTS;
  s8 qf[2][4];
#pragma unroll
  for (int g = 0; g < 2; ++g)
#pragma unroll
    for (int dt = 0; dt < 4; ++dt)
      qf[g][dt] = *(const s8*)&qtile[swz((wv & 1) * 32 + g * 16 + l15,
                                         dt * 32 + l4 * 8, DH)];

  f4 oacc[2][8];
#pragma unroll
  for (int g = 0; g < 2; ++g)
#pragma unroll
    for (int i = 0; i < 8; ++i) { oacc[g][i][0]=0.f; oacc[g][i][1]=0.f; oacc[g][i][2]=0.f; oacc[g][i][3]=0.f; }
  float m1[2] = {-INFINITY, -INFINITY}, l1[2] = {0.f, 0.f};
  const int abase = (ln & 48) + 4 * l4;  // bpermute src: lane with l15 = 4*l4+j

  // prologue: K tile 0 -> Ks[0]  (4 loads/thread outstanding)
  stage256((const char*)(gKs + hbase), (char*)&Ks[0][0], tid);

  for (int t = 0; t < ntile; ++t) {
    const int cur = t & 1;
    // issue V(t) into the single V buffer, then prefetch K(t+1)
    stage256((const char*)(gVt + hbase + (size_t)t * TILE_SHORTS), (char*)&Vt[0], tid);
    if (t + 1 < ntile) {
      stage256((const char*)(gKs + hbase + (size_t)(t + 1) * TILE_SHORTS), (char*)&Ks[cur ^ 1][0], tid);
      asm volatile("s_waitcnt vmcnt(4)" ::: "memory");   // K(t)+V(t) done, K(t+1) in flight
    } else {
      asm volatile("s_waitcnt vmcnt(0)" ::: "memory");
    }
    __builtin_amdgcn_s_barrier();
    __builtin_amdgcn_sched_barrier(0);

    if (t * 64 <= q0 + 31) {  // wave has unmasked rows in this tile
      // ---- S^T = K Q^T : D[kv = n*16+4*l4+j][q = g*16+l15]
      f4 sacc[2][4];
#pragma unroll
      for (int g = 0; g < 2; ++g)
#pragma unroll
        for (int n = 0; n < 4; ++n) { sacc[g][n][0]=0.f; sacc[g][n][1]=0.f; sacc[g][n][2]=0.f; sacc[g][n][3]=0.f; }
      __builtin_amdgcn_s_setprio(1);
#pragma unroll
      for (int n = 0; n < 4; ++n)
#pragma unroll
        for (int dt = 0; dt < 4; ++dt) {
          s8 kf = *(const s8*)&Ks[cur][swz(n * 16 + l15, dt * 32 + l4 * 8, DH)];
          sacc[0][n] = __builtin_amdgcn_mfma_f32_16x16x32_bf16(kf, qf[0][dt], sacc[0][n], 0, 0, 0);
          sacc[1][n] = __builtin_amdgcn_mfma_f32_16x16x32_bf16(kf, qf[1][dt], sacc[1][n], 0, 0, 0);
        }
      __builtin_amdgcn_s_setprio(0);

      // ---- log2-domain scores + mask + two independent softmax chains
      float z[2][4][4], mt[2], alpha[2], mold[2];
      const bool needmask = (t * 64 + 63 > q0);
#pragma unroll
      for (int g = 0; g < 2; ++g) {
        const int qg = q0 + g * 16 + l15;
        if (needmask) {
#pragma unroll
          for (int n = 0; n < 4; ++n)
#pragma unroll
            for (int j = 0; j < 4; ++j) {
              int kv = t * 64 + n * 16 + 4 * l4 + j;
              float v = sacc[g][n][j] * SC2;
              z[g][n][j] = (kv > qg) ? -INFINITY : v;
            }
        } else {
#pragma unroll
          for (int n = 0; n < 4; ++n)
#pragma unroll
            for (int j = 0; j < 4; ++j) z[g][n][j] = sacc[g][n][j] * SC2;
        }
        float a0 = fmaxf(fmaxf(z[g][0][0], z[g][0][1]), fmaxf(z[g][0][2], z[g][0][3]));
        float a1 = fmaxf(fmaxf(z[g][1][0], z[g][1][1]), fmaxf(z[g][1][2], z[g][1][3]));
        float a2 = fmaxf(fmaxf(z[g][2][0], z[g][2][1]), fmaxf(z[g][2][2], z[g][2][3]));
        float a3 = fmaxf(fmaxf(z[g][3][0], z[g][3][1]), fmaxf(z[g][3][2], z[g][3][3]));
        float m = fmaxf(fmaxf(a0, a1), fmaxf(a2, a3));
        m = fmaxf(m, __shfl_xor(m, 16));
        m = fmaxf(m, __shfl_xor(m, 32));
        mt[g] = m;
        mold[g] = m1[g];
        float mn = fmaxf(m1[g], m);
        alpha[g] = exp2f(m1[g] - mn);   // -inf - finite -> 0, never NaN
        m1[g] = mn;
        float s0 = 0.f;
#pragma unroll
        for (int n = 0; n < 4; ++n) {
#pragma unroll
          for (int j = 0; j < 4; ++j) { z[g][n][j] = exp2f(z[g][n][j] - mn); }
          s0 += (z[g][n][0] + z[g][n][1]) + (z[g][n][2] + z[g][n][3]);
        }
        s0 += __shfl_xor(s0, 16);
        s0 += __shfl_xor(s0, 32);
        l1[g] = l1[g] * alpha[g] + s0;
      }

      // ---- rescale oacc only if some lane's max actually grew (else alpha==1)
      if (__any((mt[0] > mold[0]) || (mt[1] > mold[1]))) {
#pragma unroll
        for (int g = 0; g < 2; ++g) {
          float aj[4];
#pragma unroll
          for (int j = 0; j < 4; ++j) aj[j] = lanef(alpha[g], abase + j);
#pragma unroll
          for (int ds = 0; ds < 8; ++ds)
#pragma unroll
            for (int j = 0; j < 4; ++j) oacc[g][ds][j] *= aj[j];
        }
      }

      // ---- P -> wave-local LDS tiles [q=l15][kv], packed b64 writes
#pragma unroll
      for (int g = 0; g < 2; ++g) {
        short* pw = &Ps[wv][g][0];
#pragma unroll
        for (int n = 0; n < 4; ++n) {
          unsigned lo, hi;
          asm("v_cvt_pk_bf16_f32 %0, %1, %2" : "=v"(lo) : "v"(z[g][n][0]), "v"(z[g][n][1]));
          asm("v_cvt_pk_bf16_f32 %0, %1, %2" : "=v"(hi) : "v"(z[g][n][2]), "v"(z[g][n][3]));
          uint2 w; w.x = lo; w.y = hi;
          *(uint2*)&pw[swz(l15, n * 16 + 4 * l4, KB)] = w;
        }
      }

      // ---- PV: oacc[g][q=4*l4+j][d=ds*16+l15] += P[g] * V  (V frags shared)
      s8 pa00 = *(const s8*)&Ps[wv][0][swz(l15, l4 * 8, KB)];
      s8 pa01 = *(const s8*)&Ps[wv][0][swz(l15, 32 + l4 * 8, KB)];
      s8 pa10 = *(const s8*)&Ps[wv][1][swz(l15, l4 * 8, KB)];
      s8 pa11 = *(const s8*)&Ps[wv][1][swz(l15, 32 + l4 * 8, KB)];
      __builtin_amdgcn_s_setprio(1);
#pragma unroll
      for (int ds = 0; ds < 8; ++ds) {
        s8 vb0 = *(const s8*)&Vt[swz(ds * 16 + l15, l4 * 8, KB)];
        oacc[0][ds] = __builtin_amdgcn_mfma_f32_16x16x32_bf16(pa00, vb0, oacc[0][ds], 0, 0, 0);
        oacc[1][ds] = __builtin_amdgcn_mfma_f32_16x16x32_bf16(pa10, vb0, oacc[1][ds], 0, 0, 0);
        s8 vb1 = *(const s8*)&Vt[swz(ds * 16 + l15, 32 + l4 * 8, KB)];
        oacc[0][ds] = __builtin_amdgcn_mfma_f32_16x16x32_bf16(pa01, vb1, oacc[0][ds], 0, 0, 0);
        oacc[1][ds] = __builtin_amdgcn_mfma_f32_16x16x32_bf16(pa11, vb1, oacc[1][ds], 0, 0, 0);
      }
      __builtin_amdgcn_s_setprio(0);
    }
    asm volatile("s_waitcnt lgkmcnt(0)" ::: "memory");
    __builtin_amdgcn_s_barrier();   // V buffer free for next iter's stage
    __builtin_amdgcn_sched_barrier(0);
  }

  // ---- epilogue
#pragma unroll
  for (int g = 0; g < 2; ++g) {
    float linv = 1.0f / l1[g];
    float lj[4];
#pragma unroll
    for (int j = 0; j < 4; ++j) lj[j] = lanef(linv, abase + j);
#pragma unroll
    for (int j = 0; j < 4; ++j) {
      int qg = q0 + g * 16 + 4 * l4 + j;
      float* orow = gO + ((size_t)qg * HN + h) * DH;
#pragma unroll
      for (int ds = 0; ds < 8; ++ds)
        orow[ds * 16 + l15] = oacc[g][ds][j] * lj[j];
    }
    if (l4 == 0) {
      int qg = q0 + g * 16 + l15;
      gT[h * SEQ + qg] = LN2 * (m1[g] + log2f(l1[g])) - logf((float)(qg + 1));
    }
  }
}

// ---------------------------------------------------------------- kernel 2
// 4 waves x 32 kv-rows; K rows hi/lo in regs; Qh dbuf + Ql single-buffer.
__global__ __launch_bounds__(256, 2) void corm_fwd(
    const float* __restrict__ gK, const short* __restrict__ gQh,
    const short* __restrict__ gQl, const float* __restrict__ gT,
    float* __restrict__ gC)
{
  __shared__ short Qh[2][TILE_SHORTS];   // 32 KB (dbuf)
  __shared__ short Ql[TILE_SHORTS];      // 16 KB (single)
  __shared__ float Tt[SEQ];              // 8 KB            -> 56 KB total

  const int b = blockIdx.x, h = blockIdx.y;   // b=0 heaviest, first
  const int kv0 = b * 128;
  const int tid = threadIdx.x;
  const int wv = tid >> 6, ln = tid & 63, l15 = ln & 15, l4 = ln >> 4;
  const int kvw = kv0 + wv * 32;               // wave's first kv row (32 rows)

  // wave's 32 K rows as hi/lo A-frags (two 16-row groups)
  s8 khi[2][4], klo[2][4];
#pragma unroll
  for (int g = 0; g < 2; ++g) {
    const float* krow = gK + ((size_t)(kvw + g * 16 + l15) * HN + h) * DH;
#pragma unroll
    for (int dt = 0; dt < 4; ++dt) {
      f4 a = *(const f4*)(krow + dt * 32 + l4 * 8);
      f4 bb = *(const f4*)(krow + dt * 32 + l4 * 8 + 4);
#pragma unroll
      for (int e = 0; e < 4; ++e) {
        short hi = f2bf(a[e]); khi[g][dt][e] = hi; klo[g][dt][e] = f2bf(a[e] - bf2f(hi));
        short h2 = f2bf(bb[e]); khi[g][dt][4+e] = h2; klo[g][dt][4+e] = f2bf(bb[e] - bf2f(h2));
      }
    }
  }
  for (int i = tid; i < SEQ - kv0; i += 256) Tt[i] = gT[h * SEQ + kv0 + i];
  __syncthreads();

  const size_t hbase = (size_t)h * NBLK * TILE_SHORTS;
  const int t0 = 2 * b;
  // prologue: Qh tile t0 in flight
  stage256((const char*)(gQh + hbase + (size_t)t0 * TILE_SHORTS), (char*)&Qh[t0 & 1][0], tid);

  int fired[2][4] = {{0,0,0,0},{0,0,0,0}};

  for (int t = t0; t < NBLK; ++t) {
    const int cur = t & 1;
    // issue Ql(t) into the single buffer, then prefetch Qh(t+1)
    stage256((const char*)(gQl + hbase + (size_t)t * TILE_SHORTS), (char*)&Ql[0], tid);
    if (t + 1 < NBLK) {
      stage256((const char*)(gQh + hbase + (size_t)(t + 1) * TILE_SHORTS), (char*)&Qh[cur ^ 1][0], tid);
      asm volatile("s_waitcnt vmcnt(4)" ::: "memory");   // Qh(t)+Ql(t) done
    } else {
      asm volatile("s_waitcnt vmcnt(0)" ::: "memory");
    }
    __builtin_amdgcn_s_barrier();
    __builtin_amdgcn_sched_barrier(0);

    if (kvw <= t * 64 + 63) {  // some q in tile >= wave's kv rows
      __builtin_amdgcn_s_setprio(1);
#pragma unroll
      for (int n = 0; n < 4; ++n) {
        f4 acc0, acc1;
        acc0[0]=0.f; acc0[1]=0.f; acc0[2]=0.f; acc0[3]=0.f;
        acc1[0]=0.f; acc1[1]=0.f; acc1[2]=0.f; acc1[3]=0.f;
#pragma unroll
        for (int dt = 0; dt < 4; ++dt) {
          s8 qhb = *(const s8*)&Qh[cur][swz(n * 16 + l15, dt * 32 + l4 * 8, DH)];
          s8 qlb = *(const s8*)&Ql[swz(n * 16 + l15, dt * 32 + l4 * 8, DH)];
          acc0 = __builtin_amdgcn_mfma_f32_16x16x32_bf16(khi[0][dt], qhb, acc0, 0, 0, 0);
          acc0 = __builtin_amdgcn_mfma_f32_16x16x32_bf16(khi[0][dt], qlb, acc0, 0, 0, 0);
          acc0 = __builtin_amdgcn_mfma_f32_16x16x32_bf16(klo[0][dt], qhb, acc0, 0, 0, 0);
          acc1 = __builtin_amdgcn_mfma_f32_16x16x32_bf16(khi[1][dt], qhb, acc1, 0, 0, 0);
          acc1 = __builtin_amdgcn_mfma_f32_16x16x32_bf16(khi[1][dt], qlb, acc1, 0, 0, 0);
          acc1 = __builtin_amdgcn_mfma_f32_16x16x32_bf16(klo[1][dt], qhb, acc1, 0, 0, 0);
        }
        int qg = t * 64 + n * 16 + l15;
        float Tq = Tt[qg - kv0];
#pragma unroll
        for (int j = 0; j < 4; ++j) {
          int kvr0 = kvw + 4 * l4 + j;
          if (qg >= kvr0 && acc0[j] * SCALEF >= Tq) fired[0][j] = 1;
          int kvr1 = kvw + 16 + 4 * l4 + j;
          if (qg >= kvr1 && acc1[j] * SCALEF >= Tq) fired[1][j] = 1;
        }
      }
      __builtin_amdgcn_s_setprio(0);
    }
    asm volatile("s_waitcnt lgkmcnt(0)" ::: "memory");
    __builtin_amdgcn_s_barrier();   // Ql buffer free for next iter's stage
    __builtin_amdgcn_sched_barrier(0);
  }

#pragma unroll
  for (int g = 0; g < 2; ++g)
#pragma unroll
    for (int j = 0; j < 4; ++j) {
      fired[g][j] |= __shfl_xor(fired[g][j], 1, 16);
      fired[g][j] |= __shfl_xor(fired[g][j], 2, 16);
      fired[g][j] |= __shfl_xor(fired[g][j], 4, 16);
      fired[g][j] |= __shfl_xor(fired[g][j], 8, 16);
    }
  if (l15 == 0) {
#pragma unroll
    for (int g = 0; g < 2; ++g)
#pragma unroll
      for (int j = 0; j < 4; ++j)
        gC[h * SEQ + kvw + g * 16 + 4 * l4 + j] = fired[g][j] ? 1.0f : 0.0f;
  }
}

// ---------------------------------------------------------------- launcher
extern "C" void kernel_launch(void* const* d_in, const int* in_sizes, int n_in,
                              void* d_out, int out_size, void* d_ws, size_t ws_size,
                              hipStream_t stream) {
  const float* q = (const float*)d_in[0];
  const float* k = (const float*)d_in[1];
  const float* v = (const float*)d_in[2];
  // d_in[3] = corm_mask: row i is exactly 1/(i+1); folded analytically into T.
  float* out  = (float*)d_out;
  float* corm = out + (size_t)SEQ * HN * DH;

  const size_t ARR = (size_t)HN * NBLK * TILE_SHORTS;  // 8,388,608 shorts / array
  short* Qh = (short*)d_ws;
  short* Ql = Qh + ARR;
  short* Ks = Ql + ARR;
  short* Vt = Ks + ARR;
  float* T  = (float*)(Vt + ARR);   // total ~64.3 MiB of ws

  prep_qkv<<<dim3(NBLK, HN), dim3(256), 0, stream>>>(q, k, v, Qh, Ql, Ks, Vt);
  flash_fwd<<<dim3(16, HN), dim3(256), 0, stream>>>(Qh, Ks, Vt, out, T);
  corm_fwd<<<dim3(16, HN), dim3(256), 0, stream>>>(k, Qh, Ql, T, corm);
}

// Round 6
// 220.070 us; speedup vs baseline: 1.0272x; 1.0071x over previous
//
#include <hip/hip_runtime.h>
#include <math.h>

// CORM attention v6, MI355X / gfx950.
// v6 = barrier-free. prep emits FRAGMENT-MAJOR bf16 tile images; flash/corm waves
// load MFMA fragments directly global->register (coalesced dwordx4, L1/L2-served),
// no global_load_lds, no s_barrier, no lockstep. flash keeps only wave-local P in LDS.
// v3..v5 lesson: the barriered stage pipeline pinned every wave to a ~9K-cycle
// serial chain per tile regardless of LDS size/occupancy tweaks.

#define HN   32
#define DH   128
#define SEQ  2048
#define NBLK 32            // SEQ / 64
#define KB   64
#define TILE_SHORTS 8192   // 64 * 128
#define SCALEF 0.08838834764831843f   // 1/sqrt(128)
#define SC2   0.1275174072417346f     // SCALEF * log2(e)
#define LN2   0.6931471805599453f

typedef __attribute__((ext_vector_type(4))) float f4;
typedef __attribute__((ext_vector_type(8))) short s8;

__device__ __forceinline__ short f2bf(float x) {
  union { float f; unsigned u; } a; a.f = x;
  unsigned r = a.u + 0x7FFFu + ((a.u >> 16) & 1u);  // RNE
  return (short)(r >> 16);
}
__device__ __forceinline__ float bf2f(short h) {
  union { unsigned u; float f; } a;
  a.u = ((unsigned)(unsigned short)h) << 16;
  return a.f;
}
// swizzled short-index (only used for the wave-local P tile now)
__device__ __forceinline__ int swz(int row, int colShort, int Cshort) {
  int byte = (colShort * 2) ^ ((row & 7) << 4);
  return row * Cshort + (byte >> 1);
}
__device__ __forceinline__ float lanef(float v, int srcLane) {
  return __builtin_bit_cast(float,
      __builtin_amdgcn_ds_bpermute(srcLane * 4, __builtin_bit_cast(int, v)));
}

// ---------------------------------------------------------------- prep
// Fragment-major tile images: frag index f in [0,1024) holds 16B for lane (f&63)
// of fragment (n = f>>8, dt = (f>>6)&3) i.e. rows n*16+l15, cols dt*32+l4*8.
// V^T image: f -> (ds = f>>7, half = (f>>6)&1): rows d = ds*16+l15, kv = half*32+l4*8.
__global__ __launch_bounds__(256) void prep_qkv(
    const float* __restrict__ gQ, const float* __restrict__ gK,
    const float* __restrict__ gV, short* __restrict__ oQh,
    short* __restrict__ oQl, short* __restrict__ oKs, short* __restrict__ oVt)
{
  __shared__ short Vs[64][136];
  const int blk = blockIdx.x, h = blockIdx.y, tid = threadIdx.x;
  const size_t toff = ((size_t)h * NBLK + blk) * TILE_SHORTS;

#pragma unroll
  for (int i = 0; i < 4; ++i) {
    int f = tid + 256 * i;
    int n = f >> 8, dt = (f >> 6) & 3, l4 = (f >> 4) & 3, l15 = f & 15;
    int r = n * 16 + l15, c0 = dt * 32 + l4 * 8;
    size_t rowoff = ((size_t)(blk * 64 + r) * HN + h) * DH + c0;
    {  // Q hi/lo
      f4 a = *(const f4*)(gQ + rowoff), b = *(const f4*)(gQ + rowoff + 4);
      s8 oh, ol;
#pragma unroll
      for (int e = 0; e < 4; ++e) {
        short hi = f2bf(a[e]); oh[e] = hi; ol[e] = f2bf(a[e] - bf2f(hi));
        short h2 = f2bf(b[e]); oh[4+e] = h2; ol[4+e] = f2bf(b[e] - bf2f(h2));
      }
      *(s8*)&oQh[toff + (size_t)f * 8] = oh;
      *(s8*)&oQl[toff + (size_t)f * 8] = ol;
    }
    {  // K hi
      f4 a = *(const f4*)(gK + rowoff), b = *(const f4*)(gK + rowoff + 4);
      s8 o;
#pragma unroll
      for (int e = 0; e < 4; ++e) { o[e] = f2bf(a[e]); o[4+e] = f2bf(b[e]); }
      *(s8*)&oKs[toff + (size_t)f * 8] = o;
    }
    {  // V -> LDS (linear, padded); (r,c0) is a bijection over the tile
      f4 a = *(const f4*)(gV + rowoff), b = *(const f4*)(gV + rowoff + 4);
      s8 o;
#pragma unroll
      for (int e = 0; e < 4; ++e) { o[e] = f2bf(a[e]); o[4+e] = f2bf(b[e]); }
      *(s8*)&Vs[r][c0] = o;
    }
  }
  __syncthreads();
#pragma unroll
  for (int i = 0; i < 4; ++i) {
    int f = tid + 256 * i;
    int ds = f >> 7, hf = (f >> 6) & 1, l4 = (f >> 4) & 3, l15 = f & 15;
    int d = ds * 16 + l15, k0 = hf * 32 + l4 * 8;
    s8 o;
#pragma unroll
    for (int j = 0; j < 8; ++j) o[j] = Vs[k0 + j][d];
    *(s8*)&oVt[toff + (size_t)f * 8] = o;
  }
}

// ---------------------------------------------------------------- kernel 1
// 4 waves x 32 q-rows, fully independent (no barriers). Frags from global.
__global__ __launch_bounds__(256, 2) void flash_fwd(
    const short* __restrict__ gQh, const short* __restrict__ gKs,
    const short* __restrict__ gVt, float* __restrict__ gO,
    float* __restrict__ gT)
{
  __shared__ short Ps[4][2][1024];       // 16 KB, wave-local

  const int b = (gridDim.x - 1) - blockIdx.x, h = blockIdx.y;  // heavy first
  const int tid = threadIdx.x;
  const int wv = tid >> 6, ln = tid & 63, l15 = ln & 15, l4 = ln >> 4;
  const int q0 = b * 128 + wv * 32;       // wave's first q row (32 rows)
  const size_t hbase = (size_t)h * NBLK * TILE_SHORTS;

  // Q B-frags: rows of tile 2b+(wv>>1), row-block n_q = (wv&1)*2+g
  const short* qtile = gQh + hbase + (size_t)(2 * b + (wv >> 1)) * TILE_SHORTS;
  s8 qf[2][4];
#pragma unroll
  for (int g = 0; g < 2; ++g)
#pragma unroll
    for (int dt = 0; dt < 4; ++dt)
      qf[g][dt] = *(const s8*)&qtile[(size_t)(((((wv & 1) * 2 + g) * 4 + dt) * 64 + ln)) * 8];

  f4 oacc[2][8];
#pragma unroll
  for (int g = 0; g < 2; ++g)
#pragma unroll
    for (int i = 0; i < 8; ++i) { oacc[g][i][0]=0.f; oacc[g][i][1]=0.f; oacc[g][i][2]=0.f; oacc[g][i][3]=0.f; }
  float m1[2] = {-INFINITY, -INFINITY}, l1[2] = {0.f, 0.f};
  const int abase = (ln & 48) + 4 * l4;  // bpermute src: lane with l15 = 4*l4+j

  const int ntile_w = (q0 + 31) / 64 + 1;   // per-wave causal bound

  for (int t = 0; t < ntile_w; ++t) {
    const short* kt = gKs + hbase + (size_t)t * TILE_SHORTS;
    const short* vt = gVt + hbase + (size_t)t * TILE_SHORTS;

    // ---- K fragments (16 coalesced dwordx4 loads)
    s8 kf[4][4];
#pragma unroll
    for (int n = 0; n < 4; ++n)
#pragma unroll
      for (int dt = 0; dt < 4; ++dt)
        kf[n][dt] = *(const s8*)&kt[(size_t)(((n * 4 + dt) * 64 + ln)) * 8];

    // ---- S^T = K Q^T : D[kv = n*16+4*l4+j][q = g*16+l15]
    f4 sacc[2][4];
#pragma unroll
    for (int g = 0; g < 2; ++g)
#pragma unroll
      for (int n = 0; n < 4; ++n) { sacc[g][n][0]=0.f; sacc[g][n][1]=0.f; sacc[g][n][2]=0.f; sacc[g][n][3]=0.f; }
    __builtin_amdgcn_s_setprio(1);
#pragma unroll
    for (int n = 0; n < 4; ++n)
#pragma unroll
      for (int dt = 0; dt < 4; ++dt) {
        sacc[0][n] = __builtin_amdgcn_mfma_f32_16x16x32_bf16(kf[n][dt], qf[0][dt], sacc[0][n], 0, 0, 0);
        sacc[1][n] = __builtin_amdgcn_mfma_f32_16x16x32_bf16(kf[n][dt], qf[1][dt], sacc[1][n], 0, 0, 0);
      }
    __builtin_amdgcn_s_setprio(0);

    // ---- V fragments issued now; softmax below covers their latency
    s8 vb[8][2];
#pragma unroll
    for (int ds = 0; ds < 8; ++ds)
#pragma unroll
      for (int hf = 0; hf < 2; ++hf)
        vb[ds][hf] = *(const s8*)&vt[(size_t)(((ds * 2 + hf) * 64 + ln)) * 8];

    // ---- log2-domain scores + mask + two independent softmax chains
    float z[2][4][4], mt[2], alpha[2], mold[2];
    const bool needmask = (t * 64 + 63 > q0);
#pragma unroll
    for (int g = 0; g < 2; ++g) {
      const int qg = q0 + g * 16 + l15;
      if (needmask) {
#pragma unroll
        for (int n = 0; n < 4; ++n)
#pragma unroll
          for (int j = 0; j < 4; ++j) {
            int kv = t * 64 + n * 16 + 4 * l4 + j;
            float v = sacc[g][n][j] * SC2;
            z[g][n][j] = (kv > qg) ? -INFINITY : v;
          }
      } else {
#pragma unroll
        for (int n = 0; n < 4; ++n)
#pragma unroll
          for (int j = 0; j < 4; ++j) z[g][n][j] = sacc[g][n][j] * SC2;
      }
      float a0 = fmaxf(fmaxf(z[g][0][0], z[g][0][1]), fmaxf(z[g][0][2], z[g][0][3]));
      float a1 = fmaxf(fmaxf(z[g][1][0], z[g][1][1]), fmaxf(z[g][1][2], z[g][1][3]));
      float a2 = fmaxf(fmaxf(z[g][2][0], z[g][2][1]), fmaxf(z[g][2][2], z[g][2][3]));
      float a3 = fmaxf(fmaxf(z[g][3][0], z[g][3][1]), fmaxf(z[g][3][2], z[g][3][3]));
      float m = fmaxf(fmaxf(a0, a1), fmaxf(a2, a3));
      m = fmaxf(m, __shfl_xor(m, 16));
      m = fmaxf(m, __shfl_xor(m, 32));
      mt[g] = m;
      mold[g] = m1[g];
      float mn = fmaxf(m1[g], m);
      alpha[g] = exp2f(m1[g] - mn);   // -inf - finite -> 0, never NaN
      m1[g] = mn;
      float s0 = 0.f;
#pragma unroll
      for (int n = 0; n < 4; ++n) {
#pragma unroll
        for (int j = 0; j < 4; ++j) { z[g][n][j] = exp2f(z[g][n][j] - mn); }
        s0 += (z[g][n][0] + z[g][n][1]) + (z[g][n][2] + z[g][n][3]);
      }
      s0 += __shfl_xor(s0, 16);
      s0 += __shfl_xor(s0, 32);
      l1[g] = l1[g] * alpha[g] + s0;
    }

    // ---- rescale oacc only if some lane's max actually grew (else alpha==1)
    if (__any((mt[0] > mold[0]) || (mt[1] > mold[1]))) {
#pragma unroll
      for (int g = 0; g < 2; ++g) {
        float aj[4];
#pragma unroll
        for (int j = 0; j < 4; ++j) aj[j] = lanef(alpha[g], abase + j);
#pragma unroll
        for (int ds = 0; ds < 8; ++ds)
#pragma unroll
          for (int j = 0; j < 4; ++j) oacc[g][ds][j] *= aj[j];
      }
    }

    // ---- P -> wave-local LDS tiles [q=l15][kv], packed b64 writes
#pragma unroll
    for (int g = 0; g < 2; ++g) {
      short* pw = &Ps[wv][g][0];
#pragma unroll
      for (int n = 0; n < 4; ++n) {
        unsigned lo, hi;
        asm("v_cvt_pk_bf16_f32 %0, %1, %2" : "=v"(lo) : "v"(z[g][n][0]), "v"(z[g][n][1]));
        asm("v_cvt_pk_bf16_f32 %0, %1, %2" : "=v"(hi) : "v"(z[g][n][2]), "v"(z[g][n][3]));
        uint2 w; w.x = lo; w.y = hi;
        *(uint2*)&pw[swz(l15, n * 16 + 4 * l4, KB)] = w;
      }
    }

    // ---- PV: oacc[g][q=4*l4+j][d=ds*16+l15] += P[g] * V  (V frags shared)
    s8 pa00 = *(const s8*)&Ps[wv][0][swz(l15, l4 * 8, KB)];
    s8 pa01 = *(const s8*)&Ps[wv][0][swz(l15, 32 + l4 * 8, KB)];
    s8 pa10 = *(const s8*)&Ps[wv][1][swz(l15, l4 * 8, KB)];
    s8 pa11 = *(const s8*)&Ps[wv][1][swz(l15, 32 + l4 * 8, KB)];
    __builtin_amdgcn_s_setprio(1);
#pragma unroll
    for (int ds = 0; ds < 8; ++ds) {
      oacc[0][ds] = __builtin_amdgcn_mfma_f32_16x16x32_bf16(pa00, vb[ds][0], oacc[0][ds], 0, 0, 0);
      oacc[1][ds] = __builtin_amdgcn_mfma_f32_16x16x32_bf16(pa10, vb[ds][0], oacc[1][ds], 0, 0, 0);
      oacc[0][ds] = __builtin_amdgcn_mfma_f32_16x16x32_bf16(pa01, vb[ds][1], oacc[0][ds], 0, 0, 0);
      oacc[1][ds] = __builtin_amdgcn_mfma_f32_16x16x32_bf16(pa11, vb[ds][1], oacc[1][ds], 0, 0, 0);
    }
    __builtin_amdgcn_s_setprio(0);
  }

  // ---- epilogue
#pragma unroll
  for (int g = 0; g < 2; ++g) {
    float linv = 1.0f / l1[g];
    float lj[4];
#pragma unroll
    for (int j = 0; j < 4; ++j) lj[j] = lanef(linv, abase + j);
#pragma unroll
    for (int j = 0; j < 4; ++j) {
      int qg = q0 + g * 16 + 4 * l4 + j;
      float* orow = gO + ((size_t)qg * HN + h) * DH;
#pragma unroll
      for (int ds = 0; ds < 8; ++ds)
        orow[ds * 16 + l15] = oacc[g][ds][j] * lj[j];
    }
    if (l4 == 0) {
      int qg = q0 + g * 16 + l15;
      gT[h * SEQ + qg] = LN2 * (m1[g] + log2f(l1[g])) - logf((float)(qg + 1));
    }
  }
}

// ---------------------------------------------------------------- kernel 2
// 4 waves x 32 kv-rows, zero LDS, zero barriers. K hi/lo in regs; Q frags from global.
__global__ __launch_bounds__(256, 2) void corm_fwd(
    const float* __restrict__ gK, const short* __restrict__ gQh,
    const short* __restrict__ gQl, const float* __restrict__ gT,
    float* __restrict__ gC)
{
  const int b = blockIdx.x, h = blockIdx.y;   // b=0 heaviest, first
  const int kv0 = b * 128;
  const int tid = threadIdx.x;
  const int wv = tid >> 6, ln = tid & 63, l15 = ln & 15, l4 = ln >> 4;
  const int kvw = kv0 + wv * 32;               // wave's first kv row (32 rows)

  // wave's 32 K rows as hi/lo A-frags (two 16-row groups)
  s8 khi[2][4], klo[2][4];
#pragma unroll
  for (int g = 0; g < 2; ++g) {
    const float* krow = gK + ((size_t)(kvw + g * 16 + l15) * HN + h) * DH;
#pragma unroll
    for (int dt = 0; dt < 4; ++dt) {
      f4 a = *(const f4*)(krow + dt * 32 + l4 * 8);
      f4 bb = *(const f4*)(krow + dt * 32 + l4 * 8 + 4);
#pragma unroll
      for (int e = 0; e < 4; ++e) {
        short hi = f2bf(a[e]); khi[g][dt][e] = hi; klo[g][dt][e] = f2bf(a[e] - bf2f(hi));
        short h2 = f2bf(bb[e]); khi[g][dt][4+e] = h2; klo[g][dt][4+e] = f2bf(bb[e] - bf2f(h2));
      }
    }
  }

  const size_t hbase = (size_t)h * NBLK * TILE_SHORTS;
  int fired[2][4] = {{0,0,0,0},{0,0,0,0}};
  const int t0w = kvw >> 6;   // first tile containing q >= wave's kv rows

  for (int t = t0w; t < NBLK; ++t) {
    const short* qht = gQh + hbase + (size_t)t * TILE_SHORTS;
    const short* qlt = gQl + hbase + (size_t)t * TILE_SHORTS;
#pragma unroll
    for (int n = 0; n < 4; ++n) {
      s8 qhb[4], qlb[4];
#pragma unroll
      for (int dt = 0; dt < 4; ++dt) {
        qhb[dt] = *(const s8*)&qht[(size_t)(((n * 4 + dt) * 64 + ln)) * 8];
        qlb[dt] = *(const s8*)&qlt[(size_t)(((n * 4 + dt) * 64 + ln)) * 8];
      }
      f4 acc0, acc1;
      acc0[0]=0.f; acc0[1]=0.f; acc0[2]=0.f; acc0[3]=0.f;
      acc1[0]=0.f; acc1[1]=0.f; acc1[2]=0.f; acc1[3]=0.f;
      __builtin_amdgcn_s_setprio(1);
#pragma unroll
      for (int dt = 0; dt < 4; ++dt) {
        acc0 = __builtin_amdgcn_mfma_f32_16x16x32_bf16(khi[0][dt], qhb[dt], acc0, 0, 0, 0);
        acc0 = __builtin_amdgcn_mfma_f32_16x16x32_bf16(khi[0][dt], qlb[dt], acc0, 0, 0, 0);
        acc0 = __builtin_amdgcn_mfma_f32_16x16x32_bf16(klo[0][dt], qhb[dt], acc0, 0, 0, 0);
        acc1 = __builtin_amdgcn_mfma_f32_16x16x32_bf16(khi[1][dt], qhb[dt], acc1, 0, 0, 0);
        acc1 = __builtin_amdgcn_mfma_f32_16x16x32_bf16(khi[1][dt], qlb[dt], acc1, 0, 0, 0);
        acc1 = __builtin_amdgcn_mfma_f32_16x16x32_bf16(klo[1][dt], qhb[dt], acc1, 0, 0, 0);
      }
      __builtin_amdgcn_s_setprio(0);
      int qg = t * 64 + n * 16 + l15;
      float Tq = gT[h * SEQ + qg];
#pragma unroll
      for (int j = 0; j < 4; ++j) {
        int kvr0 = kvw + 4 * l4 + j;
        if (qg >= kvr0 && acc0[j] * SCALEF >= Tq) fired[0][j] = 1;
        int kvr1 = kvw + 16 + 4 * l4 + j;
        if (qg >= kvr1 && acc1[j] * SCALEF >= Tq) fired[1][j] = 1;
      }
    }
  }

#pragma unroll
  for (int g = 0; g < 2; ++g)
#pragma unroll
    for (int j = 0; j < 4; ++j) {
      fired[g][j] |= __shfl_xor(fired[g][j], 1, 16);
      fired[g][j] |= __shfl_xor(fired[g][j], 2, 16);
      fired[g][j] |= __shfl_xor(fired[g][j], 4, 16);
      fired[g][j] |= __shfl_xor(fired[g][j], 8, 16);
    }
  if (l15 == 0) {
#pragma unroll
    for (int g = 0; g < 2; ++g)
#pragma unroll
      for (int j = 0; j < 4; ++j)
        gC[h * SEQ + kvw + g * 16 + 4 * l4 + j] = fired[g][j] ? 1.0f : 0.0f;
  }
}

// ---------------------------------------------------------------- launcher
extern "C" void kernel_launch(void* const* d_in, const int* in_sizes, int n_in,
                              void* d_out, int out_size, void* d_ws, size_t ws_size,
                              hipStream_t stream) {
  const float* q = (const float*)d_in[0];
  const float* k = (const float*)d_in[1];
  const float* v = (const float*)d_in[2];
  // d_in[3] = corm_mask: row i is exactly 1/(i+1); folded analytically into T.
  float* out  = (float*)d_out;
  float* corm = out + (size_t)SEQ * HN * DH;

  const size_t ARR = (size_t)HN * NBLK * TILE_SHORTS;  // 8,388,608 shorts / array
  short* Qh = (short*)d_ws;
  short* Ql = Qh + ARR;
  short* Ks = Ql + ARR;
  short* Vt = Ks + ARR;
  float* T  = (float*)(Vt + ARR);   // total ~64.3 MiB of ws

  prep_qkv<<<dim3(NBLK, HN), dim3(256), 0, stream>>>(q, k, v, Qh, Ql, Ks, Vt);
  flash_fwd<<<dim3(16, HN), dim3(256), 0, stream>>>(Qh, Ks, Vt, out, T);
  corm_fwd<<<dim3(16, HN), dim3(256), 0, stream>>>(k, Qh, Ql, T, corm);
}